// Round 20
// baseline (8840.881 us; speedup 1.0000x reference)
//
#include <hip/hip_runtime.h>

#define B_  64
#define T_  2048
#define I_  128
#define H_  256
#define G4  1024   // 4*H
#define TC  128    // timestep chunk

// W chunk = 8 h-dims x 1024 gate-rows. 32 chunks total.
// Chunks 0..QC-1 (dims 0..151): INT8 in LDS (152 KB).
// Chunks QC..31  (dims 152..255): f16, streamed from L2 each step,
//   r13-style plain uint4 loads (the only shape measured to hit the
//   64 B/cy per-CU L1-return port ceiling). 208 KB/step vs r13's 368.
#define QC  19
#define SC  13
#define SC8 (1.0f / 2032.0f)   // w ~ U(-1/16,1/16): q = rint(w*2032)

typedef float    f32x4 __attribute__((ext_vector_type(4)));
typedef _Float16 f16x8 __attribute__((ext_vector_type(8)));
typedef _Float16 f16x2 __attribute__((ext_vector_type(2)));

__device__ __forceinline__ float dot2f(unsigned w, unsigned h, float acc) {
#if __has_builtin(__builtin_amdgcn_fdot2)
  return __builtin_amdgcn_fdot2(__builtin_bit_cast(f16x2, w),
                                __builtin_bit_cast(f16x2, h), acc, false);
#else
  f16x2 a = __builtin_bit_cast(f16x2, w), b = __builtin_bit_cast(f16x2, h);
  return acc + (float)a[0] * (float)b[0] + (float)a[1] * (float)b[1];
#endif
}

// int8->f16x2 via 0x6400 bias trick: f16 bits (0x6400 | b) == 1024 + b exactly.
__device__ __forceinline__ unsigned prm01(unsigned v) {
#if __has_builtin(__builtin_amdgcn_perm)
  return __builtin_amdgcn_perm(v, 0x64646464u, 0x00050004u);  // bytes 0,1
#else
  return 0x64006400u | (v & 0xffu) | ((v & 0xff00u) << 8);
#endif
}
__device__ __forceinline__ unsigned prm23(unsigned v) {
#if __has_builtin(__builtin_amdgcn_perm)
  return __builtin_amdgcn_perm(v, 0x64646464u, 0x00070006u);  // bytes 2,3
#else
  return 0x64006400u | ((v >> 16) & 0xffu) | ((v & 0xff000000u) >> 8);
#endif
}

__device__ __forceinline__ unsigned short h16bits(float f) {
  return __builtin_bit_cast(unsigned short, (_Float16)f);
}
__device__ __forceinline__ float sigm(float x) { return 1.f / (1.f + __expf(-x)); }
__device__ __forceinline__ float tanh_fast(float x) { return 2.f / (1.f + __expf(-2.f * x)) - 1.f; }

// ---------------- prep kernels ----------------

// f16 wall (stream tier reads chunks QC..31; writes all 32, harmless)
__global__ void prep_w(const float* __restrict__ Whh, uint4* __restrict__ wall) {
  int idx = blockIdx.x * 256 + threadIdx.x;
  if (idx >= 32 * 1024) return;
  int c4 = idx >> 10, r = idx & 1023;
  unsigned q[4];
#pragma unroll
  for (int m = 0; m < 4; m++) {
    int kd = 4 * c4 + m;
    unsigned lo = h16bits(Whh[r * 256 + 2 * kd]);
    unsigned hi = h16bits(Whh[r * 256 + 2 * kd + 1]);
    q[m] = lo | (hi << 16);
  }
  wall[c4 * 1024 + r] = make_uint4(q[0], q[1], q[2], q[3]);
}

// int8 wall for chunks 0..QC-1 (dims 0..8*QC-1): uint2 per (chunk,row)
__global__ void prep_w8(const float* __restrict__ Whh, uint2* __restrict__ w8) {
  int idx = blockIdx.x * 256 + threadIdx.x;
  if (idx >= QC * 1024) return;
  int c = idx >> 10, r = idx & 1023;
  const float* src = Whh + r * 256 + c * 8;
  unsigned lo = 0, hi = 0;
#pragma unroll
  for (int jj = 0; jj < 4; jj++) {
    int q = (int)rintf(src[jj] * 2032.0f) + 128;
    q = q < 0 ? 0 : (q > 255 ? 255 : q);
    lo |= (unsigned)q << (8 * jj);
  }
#pragma unroll
  for (int jj = 4; jj < 8; jj++) {
    int q = (int)rintf(src[jj] * 2032.0f) + 128;
    q = q < 0 ? 0 : (q > 255 ? 255 : q);
    hi |= (unsigned)q << (8 * (jj - 4));
  }
  w8[c * 1024 + r] = make_uint2(lo, hi);
}

__global__ void prep_f16(const float* __restrict__ src, _Float16* __restrict__ dst, int n) {
  int i = blockIdx.x * 256 + threadIdx.x;
  if (i < n) dst[i] = (_Float16)src[i];
}

__global__ void prep_bias(const float* __restrict__ bi, const float* __restrict__ bh,
                          float* __restrict__ bias) {
  int i = blockIdx.x * 256 + threadIdx.x;
  if (i < G4) bias[i] = bi[i] + bh[i];
}

// ---------------- projection GEMM (f16 MFMA), xw stored f16 ----------------
template <int K, bool SRC_F32>
__global__ __launch_bounds__(256) void proj_kernel(const void* __restrict__ Asrc,
                                                   const _Float16* __restrict__ Wf,
                                                   const float* __restrict__ bias,
                                                   _Float16* __restrict__ xw, int t0) {
  const int m  = blockIdx.x;
  const int n0 = blockIdx.y * 64;
  const int tid = threadIdx.x;
  const int lane = tid & 63, wv = tid >> 6;

  __shared__ _Float16 As[64][40];
  __shared__ _Float16 Bs[64][40];

  f32x4 acc[4] = {f32x4{0,0,0,0}, f32x4{0,0,0,0}, f32x4{0,0,0,0}, f32x4{0,0,0,0}};

  const int r  = tid >> 2;
  const int kq = (tid & 3) * 8;
  const int r_g = m * 64 + r;
  const int b  = r_g >> 7;          // TC = 128
  const int tc = r_g & (TC - 1);
  long arow;
  if (SRC_F32) arow = (long)(b * T_ + t0 + tc) * K;
  else         arow = (long)r_g * K;

  for (int k0 = 0; k0 < K; k0 += 32) {
    if (SRC_F32) {
      const float* ap = (const float*)Asrc + arow + k0 + kq;
      float4 a0 = *(const float4*)ap;
      float4 a1 = *(const float4*)(ap + 4);
      _Float16* d = &As[r][kq];
      d[0] = (_Float16)a0.x; d[1] = (_Float16)a0.y; d[2] = (_Float16)a0.z; d[3] = (_Float16)a0.w;
      d[4] = (_Float16)a1.x; d[5] = (_Float16)a1.y; d[6] = (_Float16)a1.z; d[7] = (_Float16)a1.w;
    } else {
      const _Float16* ap = (const _Float16*)Asrc + arow + k0 + kq;
      *(uint4*)&As[r][kq] = *(const uint4*)ap;
    }
    *(uint4*)&Bs[r][kq] = *(const uint4*)(Wf + (long)(n0 + r) * K + k0 + kq);
    __syncthreads();

    f16x8 av = *(const f16x8*)&As[wv * 16 + (lane & 15)][(lane >> 4) * 8];
#pragma unroll
    for (int q = 0; q < 4; q++) {
      f16x8 bv = *(const f16x8*)&Bs[q * 16 + (lane & 15)][(lane >> 4) * 8];
      acc[q] = __builtin_amdgcn_mfma_f32_16x16x32_f16(av, bv, acc[q], 0, 0, 0);
    }
    __syncthreads();
  }

  const int row_in = wv * 16 + ((lane >> 4) << 2);
  const int col_in = lane & 15;
#pragma unroll
  for (int q = 0; q < 4; q++) {
#pragma unroll
    for (int i = 0; i < 4; i++) {
      int rr = m * 64 + row_in + i;
      int cc = n0 + q * 16 + col_in;
      xw[(long)rr * G4 + cc] = (_Float16)(acc[q][i] + bias[cc]);
    }
  }
}

// ---------------- recurrent scan ----------------
// One block (512 threads, 8 waves) per (batch, layer-job). Thread t:
// p=t&255, s=t>>8; rows r0=p+s*256 (i or f), r1=r0+512 (g or o).
//   s=0 -> computes pig = sigm(i)*tanh(g);  s=1 -> (f,o) + owns c/h state.
// Tiers: 19 chunks INT8 in LDS (152 KB; ds_read_b64 at 2-way aliasing =
// conflict-free) + 13 chunks f16 streamed exactly like r13 (plain uint4
// loop, no pins — the only stream shape measured at the 64 B/cy port
// ceiling; r16/r17/r18's manual pipelines were all latency-bound).
// Dequant: perm 0x6400 trick (value 1024+b exact); constant removed once
// per row via 1152*Hsum, Hsum = sum of f16-rounded h over dims 0..151,
// computed per step by a shfl butterfly on the s==1 half (r18-validated).
// A launch carries TWO jobs (L0 chunk k, L1 chunk k-1) on disjoint blocks.

struct ScanJob {
  const _Float16* xw;      // [B*TC][1024] f16
  const uint4*    wall;    // [32][1024] f16 pairs
  const uint2*    w8;      // [QC][1024] int8 (biased)
  const float*    mask;    // [B][256]
  float* hstate; float* cstate;
  _Float16* ychunk;        // layer0 output chunk (or null)
  float* out;              // layer1: d_out base (or null)
  float* hn; float* cn;    // last chunk only (or null)
  int t0; int valid;
};

// 8 dots per f16 chunk over 4 accumulator chains
#define DOT2(gA, gB, c) { uint4 hv = hs4[c]; \
  a0 = dot2f(gA.x, hv.x, a0); a1 = dot2f(gB.x, hv.x, a1); \
  b0 = dot2f(gA.y, hv.y, b0); b1 = dot2f(gB.y, hv.y, b1); \
  a0 = dot2f(gA.z, hv.z, a0); a1 = dot2f(gB.z, hv.z, a1); \
  b0 = dot2f(gA.w, hv.w, b0); b1 = dot2f(gB.w, hv.w, b1); }

// int8 dword -> 2 biased f16x2 -> 2 fdot2 on two chains
#define DQ(vw, h1, h2, qa, qb) \
  qa = dot2f(prm01(vw), h1, qa); \
  qb = dot2f(prm23(vw), h2, qb);

__global__ __launch_bounds__(512, 1) void scan_kernel(ScanJob j0, ScanJob j1) {
  ScanJob j = (blockIdx.x < B_) ? j0 : j1;
  if (!j.valid) return;
  const int b = blockIdx.x & (B_ - 1);
  const int t = threadIdx.x;
  const int p = t & 255, s = t >> 8;
  const int r0 = p + s * 256;
  const int r1 = r0 + 512;

  __shared__ uint2 wq8[QC * 1024];                     // 155648 B int8 tier
  __shared__ __align__(16) unsigned short hsm[256];    // h packed f16
  __shared__ float pig[256];                           // sigm(i)*tanh(g)
  __shared__ float hpart[4];                           // Hsum wave partials

  // stage int8 tier into LDS (linear copy, coalesced)
#pragma unroll
  for (int i = 0; i < QC * 2; i++)
    wq8[i * 512 + t] = j.w8[i * 512 + t];

  float c_reg = 0.f, h_reg = 0.f, mk = 0.f;
  if (s == 1) {
    c_reg = j.cstate[b * 256 + p];
    mk    = j.mask[b * 256 + p];
    // initial Hsum over f16-rounded h, dims 0..8*QC-1
    _Float16 hf = (_Float16)j.hstate[b * 256 + p];
    float v = (p < QC * 8) ? (float)hf : 0.0f;
    v += __shfl_xor(v, 1, 64);  v += __shfl_xor(v, 2, 64);
    v += __shfl_xor(v, 4, 64);  v += __shfl_xor(v, 8, 64);
    v += __shfl_xor(v, 16, 64); v += __shfl_xor(v, 32, 64);
    if ((t & 63) == 0) hpart[(t >> 6) & 3] = v;
  } else {
    hsm[p] = h16bits(j.hstate[b * 256 + p]);
  }
  __syncthreads();

  const uint4* hs4 = (const uint4*)hsm;
  const _Float16* xwb = j.xw + (long)b * TC * G4;
  float xA = (float)xwb[r0], xB = (float)xwb[r1];
  float hm_prev = 0.f;

  for (int tc = 0; tc < TC; ++tc) {
    const float Hsum = (hpart[0] + hpart[1]) + (hpart[2] + hpart[3]);

    // prefetch next step's xw
    float nA = 0.f, nB = 0.f;
    if (tc + 1 < TC) {
      nA = (float)xwb[(long)(tc + 1) * G4 + r0];
      nB = (float)xwb[(long)(tc + 1) * G4 + r1];
    }

    // deferred output store for previous step
    if (s == 1 && tc > 0) {
      if (j.ychunk) j.ychunk[(b * TC + tc - 1) * H_ + p] = (_Float16)hm_prev;
      else          j.out[(long)(b * T_ + j.t0 + tc - 1) * H_ + p] = hm_prev;
    }

    float a0 = xA, a1 = xB, b0 = 0.f, b1 = 0.f;
    float qa0 = 0.f, qb0 = 0.f, qa1 = 0.f, qb1 = 0.f;

    // ---- f16 stream tier (chunks QC..31): r13's exact shape — plain
    // unrolled full-width uint4 loads, compiler-scheduled, no pins
    const uint4* wsp = j.wall + QC * 1024;
    asm volatile("" : "+v"(wsp));   // opaque: no hoist across iterations
#pragma unroll
    for (int m = 0; m < SC; m++) {
      uint4 sA = wsp[m * 1024 + r0];
      uint4 sB = wsp[m * 1024 + r1];
      DOT2(sA, sB, QC + m)
    }

    // ---- int8 LDS tier (chunks 0..QC-1)
#pragma unroll
    for (int m = 0; m < QC; m++) {
      uint2 vA = wq8[m * 1024 + r0];
      uint2 vB = wq8[m * 1024 + r1];
      uint4 hv = hs4[m];
      DQ(vA.x, hv.x, hv.y, qa0, qb0) DQ(vA.y, hv.z, hv.w, qa0, qb0)
      DQ(vB.x, hv.x, hv.y, qa1, qb1) DQ(vB.y, hv.z, hv.w, qa1, qb1)
    }

    const float corr = 1152.0f * Hsum;
    float aF = a0 + b0 + (qa0 + qb0 - corr) * SC8;  // s=0: pre_i ; s=1: pre_f
    float bF = a1 + b1 + (qa1 + qb1 - corr) * SC8;  // s=0: pre_g ; s=1: pre_o

    if (s == 0) pig[p] = sigm(aF) * tanh_fast(bF);
    __syncthreads();
    if (s == 1) {
      c_reg = sigm(aF) * c_reg + pig[p];
      h_reg = sigm(bF) * tanh_fast(c_reg);
      _Float16 hf = (_Float16)h_reg;
      hsm[p] = __builtin_bit_cast(unsigned short, hf);
      hm_prev = h_reg * mk;
      // Hsum for the NEXT step
      float v = (p < QC * 8) ? (float)hf : 0.0f;
      v += __shfl_xor(v, 1, 64);  v += __shfl_xor(v, 2, 64);
      v += __shfl_xor(v, 4, 64);  v += __shfl_xor(v, 8, 64);
      v += __shfl_xor(v, 16, 64); v += __shfl_xor(v, 32, 64);
      if ((t & 63) == 0) hpart[(t >> 6) & 3] = v;
    }
    xA = nA; xB = nB;
    __syncthreads();
  }

  if (s == 1) {
    if (j.ychunk) j.ychunk[(b * TC + TC - 1) * H_ + p] = (_Float16)hm_prev;
    else          j.out[(long)(b * T_ + j.t0 + TC - 1) * H_ + p] = hm_prev;
    j.hstate[b * 256 + p] = h_reg;
    j.cstate[b * 256 + p] = c_reg;
    if (j.hn) { j.hn[b * 256 + p] = h_reg; j.cn[b * 256 + p] = c_reg; }
  }
}

// ---------------- host launch ----------------
extern "C" void kernel_launch(void* const* d_in, const int* in_sizes, int n_in,
                              void* d_out, int out_size, void* d_ws, size_t ws_size,
                              hipStream_t stream) {
  const float* x     = (const float*)d_in[0];
  const float* Wih0  = (const float*)d_in[1];
  const float* Whh0  = (const float*)d_in[2];
  const float* bih0  = (const float*)d_in[3];
  const float* bhh0  = (const float*)d_in[4];
  const float* mask0 = (const float*)d_in[5];
  const float* Wih1  = (const float*)d_in[6];
  const float* Whh1  = (const float*)d_in[7];
  const float* bih1  = (const float*)d_in[8];
  const float* bhh1  = (const float*)d_in[9];
  const float* mask1 = (const float*)d_in[10];

  float* out = (float*)d_out;
  float* hn  = out + (long)B_ * T_ * H_;   // [2][64][256]
  float* cn  = hn + 2 * B_ * H_;

  char* w = (char*)d_ws;
  uint4*    wall0  = (uint4*)w;      w += 512 << 10;   // [32][1024] uint4
  uint4*    wall1  = (uint4*)w;      w += 512 << 10;
  uint2*    w8_0   = (uint2*)w;      w += 192 << 10;   // [QC][1024] uint2
  uint2*    w8_1   = (uint2*)w;      w += 192 << 10;
  _Float16* wf0    = (_Float16*)w;   w += 256 << 10;
  _Float16* wf1    = (_Float16*)w;   w += 512 << 10;
  float*    bias0  = (float*)w;      w += 4 << 10;
  float*    bias1  = (float*)w;      w += 4 << 10;
  float*    h0s    = (float*)w;      w += 64 << 10;
  float*    c0s    = (float*)w;      w += 64 << 10;
  float*    h1s    = (float*)w;      w += 64 << 10;
  float*    c1s    = (float*)w;      w += 64 << 10;
  _Float16* xw0    = (_Float16*)w;   w += (long)B_ * TC * G4 * 2;   // 16 MB
  _Float16* xw1    = (_Float16*)w;   w += (long)B_ * TC * G4 * 2;   // 16 MB
  _Float16* ybuf   = (_Float16*)w;   w += (long)B_ * TC * H_ * 2;   // 4 MB

  hipMemsetAsync(h0s, 0, 4 * (64 << 10), stream);

  prep_w<<<128, 256, 0, stream>>>(Whh0, wall0);
  prep_w<<<128, 256, 0, stream>>>(Whh1, wall1);
  prep_w8<<<(QC * 1024 + 255) / 256, 256, 0, stream>>>(Whh0, w8_0);
  prep_w8<<<(QC * 1024 + 255) / 256, 256, 0, stream>>>(Whh1, w8_1);
  prep_f16<<<512, 256, 0, stream>>>(Wih0, wf0, G4 * I_);
  prep_f16<<<1024, 256, 0, stream>>>(Wih1, wf1, G4 * H_);
  prep_bias<<<4, 256, 0, stream>>>(bih0, bhh0, bias0);
  prep_bias<<<4, 256, 0, stream>>>(bih1, bhh1, bias1);

  const int nchunk = T_ / TC;  // 16
  for (int k = 0; k <= nchunk; k++) {
    if (k < nchunk) {
      proj_kernel<I_, true><<<dim3(B_ * TC / 64, G4 / 64), 256, 0, stream>>>(
          x, wf0, bias0, xw0, k * TC);
    }
    ScanJob j0, j1;
    // layer 0, chunk k
    j0.xw = xw0; j0.wall = wall0; j0.w8 = w8_0; j0.mask = mask0;
    j0.hstate = h0s; j0.cstate = c0s;
    j0.ychunk = ybuf; j0.out = nullptr;
    j0.hn = (k == nchunk - 1) ? hn : nullptr;
    j0.cn = (k == nchunk - 1) ? cn : nullptr;
    j0.t0 = k * TC; j0.valid = (k < nchunk);
    // layer 1, chunk k-1
    j1.xw = xw1; j1.wall = wall1; j1.w8 = w8_1; j1.mask = mask1;
    j1.hstate = h1s; j1.cstate = c1s;
    j1.ychunk = nullptr; j1.out = out;
    j1.hn = (k == nchunk) ? hn + B_ * H_ : nullptr;
    j1.cn = (k == nchunk) ? cn + B_ * H_ : nullptr;
    j1.t0 = (k - 1) * TC; j1.valid = (k >= 1);

    scan_kernel<<<2 * B_, 512, 0, stream>>>(j0, j1);

    if (k < nchunk) {
      proj_kernel<H_, false><<<dim3(B_ * TC / 64, G4 / 64), 256, 0, stream>>>(
          ybuf, wf1, bias1, xw1, k * TC);
    }
  }
}

// Round 21
// 5334.686 us; speedup vs baseline: 1.6572x; 1.6572x over previous
//
#include <hip/hip_runtime.h>

#define B_  64
#define T_  2048
#define I_  128
#define H_  256
#define G4  1024   // 4*H
#define TC  128    // timestep chunk

// W chunk tiers (chunk = uint4 per gate-row = 8 h-dims; 32 chunks total)
#define HC  23     // chunks 0..22: compiler-scheduled L2 stream (see note)
#define MC  9      // chunks 23..31 LDS-resident (147456 B)

typedef float    f32x4 __attribute__((ext_vector_type(4)));
typedef _Float16 f16x8 __attribute__((ext_vector_type(8)));
typedef _Float16 f16x2 __attribute__((ext_vector_type(2)));

__device__ __forceinline__ float dot2f(unsigned w, unsigned h, float acc) {
#if __has_builtin(__builtin_amdgcn_fdot2)
  return __builtin_amdgcn_fdot2(__builtin_bit_cast(f16x2, w),
                                __builtin_bit_cast(f16x2, h), acc, false);
#else
  f16x2 a = __builtin_bit_cast(f16x2, w), b = __builtin_bit_cast(f16x2, h);
  return acc + (float)a[0] * (float)b[0] + (float)a[1] * (float)b[1];
#endif
}

__device__ __forceinline__ unsigned short h16bits(float f) {
  return __builtin_bit_cast(unsigned short, (_Float16)f);
}
__device__ __forceinline__ float sigm(float x) { return 1.f / (1.f + __expf(-x)); }
__device__ __forceinline__ float tanh_fast(float x) { return 2.f / (1.f + __expf(-2.f * x)) - 1.f; }

// ---------------- prep kernels ----------------

__global__ void prep_w(const float* __restrict__ Whh, uint4* __restrict__ wall) {
  int idx = blockIdx.x * 256 + threadIdx.x;
  if (idx >= 32 * 1024) return;
  int c4 = idx >> 10, r = idx & 1023;
  unsigned q[4];
#pragma unroll
  for (int m = 0; m < 4; m++) {
    int kd = 4 * c4 + m;
    unsigned lo = h16bits(Whh[r * 256 + 2 * kd]);
    unsigned hi = h16bits(Whh[r * 256 + 2 * kd + 1]);
    q[m] = lo | (hi << 16);
  }
  wall[c4 * 1024 + r] = make_uint4(q[0], q[1], q[2], q[3]);
}

__global__ void prep_f16(const float* __restrict__ src, _Float16* __restrict__ dst, int n) {
  int i = blockIdx.x * 256 + threadIdx.x;
  if (i < n) dst[i] = (_Float16)src[i];
}

__global__ void prep_bias(const float* __restrict__ bi, const float* __restrict__ bh,
                          float* __restrict__ bias) {
  int i = blockIdx.x * 256 + threadIdx.x;
  if (i < G4) bias[i] = bi[i] + bh[i];
}

// ---------------- projection GEMM (f16 MFMA), xw stored f16 ----------------
template <int K, bool SRC_F32>
__global__ __launch_bounds__(256) void proj_kernel(const void* __restrict__ Asrc,
                                                   const _Float16* __restrict__ Wf,
                                                   const float* __restrict__ bias,
                                                   _Float16* __restrict__ xw, int t0) {
  const int m  = blockIdx.x;
  const int n0 = blockIdx.y * 64;
  const int tid = threadIdx.x;
  const int lane = tid & 63, wv = tid >> 6;

  __shared__ _Float16 As[64][40];
  __shared__ _Float16 Bs[64][40];

  f32x4 acc[4] = {f32x4{0,0,0,0}, f32x4{0,0,0,0}, f32x4{0,0,0,0}, f32x4{0,0,0,0}};

  const int r  = tid >> 2;
  const int kq = (tid & 3) * 8;
  const int r_g = m * 64 + r;
  const int b  = r_g >> 7;          // TC = 128
  const int tc = r_g & (TC - 1);
  long arow;
  if (SRC_F32) arow = (long)(b * T_ + t0 + tc) * K;
  else         arow = (long)r_g * K;

  for (int k0 = 0; k0 < K; k0 += 32) {
    if (SRC_F32) {
      const float* ap = (const float*)Asrc + arow + k0 + kq;
      float4 a0 = *(const float4*)ap;
      float4 a1 = *(const float4*)(ap + 4);
      _Float16* d = &As[r][kq];
      d[0] = (_Float16)a0.x; d[1] = (_Float16)a0.y; d[2] = (_Float16)a0.z; d[3] = (_Float16)a0.w;
      d[4] = (_Float16)a1.x; d[5] = (_Float16)a1.y; d[6] = (_Float16)a1.z; d[7] = (_Float16)a1.w;
    } else {
      const _Float16* ap = (const _Float16*)Asrc + arow + k0 + kq;
      *(uint4*)&As[r][kq] = *(const uint4*)ap;
    }
    *(uint4*)&Bs[r][kq] = *(const uint4*)(Wf + (long)(n0 + r) * K + k0 + kq);
    __syncthreads();

    f16x8 av = *(const f16x8*)&As[wv * 16 + (lane & 15)][(lane >> 4) * 8];
#pragma unroll
    for (int q = 0; q < 4; q++) {
      f16x8 bv = *(const f16x8*)&Bs[q * 16 + (lane & 15)][(lane >> 4) * 8];
      acc[q] = __builtin_amdgcn_mfma_f32_16x16x32_f16(av, bv, acc[q], 0, 0, 0);
    }
    __syncthreads();
  }

  const int row_in = wv * 16 + ((lane >> 4) << 2);
  const int col_in = lane & 15;
#pragma unroll
  for (int q = 0; q < 4; q++) {
#pragma unroll
    for (int i = 0; i < 4; i++) {
      int rr = m * 64 + row_in + i;
      int cc = n0 + q * 16 + col_in;
      xw[(long)rr * G4 + cc] = (_Float16)(acc[q][i] + bias[cc]);
    }
  }
}

// ---------------- recurrent scan ----------------
// CHAMPION CONFIG (r13/r15, measured 303 us/dispatch, 5.34 ms total).
// One block (512 threads, 8 waves) per (batch, layer-job). Thread t:
// p=t&255, s=t>>8; rows r0=p+s*256 (i or f), r1=r0+512 (g or o).
//   s=0 -> computes pig = sigm(i)*tanh(g);  s=1 -> (f,o) + owns c/h state.
// 23 chunks declared as pinned registers; the RA (hard 128-VGPR cap on
// 512-thr blocks) rematerializes them into per-step L2 loads which the
// compiler schedules to the per-CU L2->L1 port CEILING (measured 64.7 B/cy
// = m56's 60 B/cy L2 ceiling). 9 chunks in LDS (147 KB). Off-CU traffic =
// 368 KB/step = the provable minimum (512 KB W - 147 KB LDS; registers
// cannot hold W: 14 configs r2-r17). Floor = 368KB/64B/cy = 2.34 us/step;
// measured 2.37. r14-r20 variants (honest pins, manual pipelines, int8
// stream/LDS) all broke this load-scheduling regime and ran 20-100% slower.
// A launch carries TWO jobs (L0 chunk k, L1 chunk k-1) on disjoint blocks.

struct ScanJob {
  const _Float16* xw;      // [B*TC][1024] f16
  const uint4*    wall;    // [32][1024]
  const float*    mask;    // [B][256]
  float* hstate; float* cstate;
  _Float16* ychunk;        // layer0 output chunk (or null)
  float* out;              // layer1: d_out base (or null)
  float* hn; float* cn;    // last chunk only (or null)
  int t0; int valid;
};

#define C23(X) X(0) X(1) X(2) X(3) X(4) X(5) X(6) X(7) X(8) X(9) X(10) X(11) \
               X(12) X(13) X(14) X(15) X(16) X(17) X(18) X(19) X(20) X(21) X(22)

#define LOADW(i) \
  uint4 wA_##i = wall_p[(i) * 1024 + r0]; \
  uint4 wB_##i = wall_p[(i) * 1024 + r1];

#define PINW(i) \
  asm volatile("" : "+v"(wA_##i.x), "+v"(wA_##i.y), "+v"(wA_##i.z), "+v"(wA_##i.w), \
                    "+v"(wB_##i.x), "+v"(wB_##i.y), "+v"(wB_##i.z), "+v"(wB_##i.w));

// 8 dots per chunk over 4 accumulator chains
#define DOT2(gA, gB, c) { uint4 hv = hs4[c]; \
  a0 = dot2f(gA.x, hv.x, a0); a1 = dot2f(gB.x, hv.x, a1); \
  b0 = dot2f(gA.y, hv.y, b0); b1 = dot2f(gB.y, hv.y, b1); \
  a0 = dot2f(gA.z, hv.z, a0); a1 = dot2f(gB.z, hv.z, a1); \
  b0 = dot2f(gA.w, hv.w, b0); b1 = dot2f(gB.w, hv.w, b1); }

#define DOTR(i)  DOT2(wA_##i, wB_##i, i)

__global__ __launch_bounds__(512, 1) void scan_kernel(ScanJob j0, ScanJob j1) {
  ScanJob j = (blockIdx.x < B_) ? j0 : j1;
  if (!j.valid) return;
  const int b = blockIdx.x & (B_ - 1);
  const int t = threadIdx.x;
  const int p = t & 255, s = t >> 8;
  const int r0 = p + s * 256;
  const int r1 = r0 + 512;

  __shared__ uint4 wmid[MC * 1024];                    // 147456 B
  __shared__ __align__(16) unsigned short hsm[256];    // h packed f16
  __shared__ float pig[256];                           // sigm(i)*tanh(g)

  const uint4* wall_p = j.wall;

  // stage LDS tier (chunks HC..31, coalesced)
#pragma unroll
  for (int i = 0; i < MC * 2; i++)
    wmid[i * 512 + t] = wall_p[HC * 1024 + i * 512 + t];

  // "register tier": chunks 0..22 — RA remats these into loop-resident
  // L2 loads; this exact shape is what reaches the port ceiling.
  C23(LOADW)
  C23(PINW)

  float c_reg = 0.f, h_reg = 0.f, mk = 0.f;
  if (s == 1) {
    c_reg = j.cstate[b * 256 + p];
    mk    = j.mask[b * 256 + p];
  } else {
    hsm[p] = h16bits(j.hstate[b * 256 + p]);
  }
  __syncthreads();

  const uint4* hs4 = (const uint4*)hsm;
  const _Float16* xwb = j.xw + (long)b * TC * G4;
  float xA = (float)xwb[r0], xB = (float)xwb[r1];
  float hm_prev = 0.f;

  for (int tc = 0; tc < TC; ++tc) {
    // prefetch next step's xw
    float nA = 0.f, nB = 0.f;
    if (tc + 1 < TC) {
      nA = (float)xwb[(long)(tc + 1) * G4 + r0];
      nB = (float)xwb[(long)(tc + 1) * G4 + r1];
    }

    // deferred output store for previous step (drain hides under the dots)
    if (s == 1 && tc > 0) {
      if (j.ychunk) j.ychunk[(b * TC + tc - 1) * H_ + p] = (_Float16)hm_prev;
      else          j.out[(long)(b * T_ + j.t0 + tc - 1) * H_ + p] = hm_prev;
    }

    float a0 = xA, a1 = xB, b0 = 0.f, b1 = 0.f;

    // stream tier (23 chunks)
    C23(DOTR)

    // LDS tier (9 chunks)
#pragma unroll
    for (int m = 0; m < MC; m++) {
      uint4 tA = wmid[m * 1024 + r0];
      uint4 tB = wmid[m * 1024 + r1];
      DOT2(tA, tB, HC + m)
    }

    float aF = a0 + b0;   // s=0: pre_i ; s=1: pre_f
    float bF = a1 + b1;   // s=0: pre_g ; s=1: pre_o

    if (s == 0) pig[p] = sigm(aF) * tanh_fast(bF);
    __syncthreads();
    if (s == 1) {
      c_reg = sigm(aF) * c_reg + pig[p];
      h_reg = sigm(bF) * tanh_fast(c_reg);
      hsm[p] = h16bits(h_reg);
      hm_prev = h_reg * mk;
    }
    xA = nA; xB = nB;
    __syncthreads();
  }

  if (s == 1) {
    if (j.ychunk) j.ychunk[(b * TC + TC - 1) * H_ + p] = (_Float16)hm_prev;
    else          j.out[(long)(b * T_ + j.t0 + TC - 1) * H_ + p] = hm_prev;
    j.hstate[b * 256 + p] = h_reg;
    j.cstate[b * 256 + p] = c_reg;
    if (j.hn) { j.hn[b * 256 + p] = h_reg; j.cn[b * 256 + p] = c_reg; }
  }
}

// ---------------- host launch ----------------
extern "C" void kernel_launch(void* const* d_in, const int* in_sizes, int n_in,
                              void* d_out, int out_size, void* d_ws, size_t ws_size,
                              hipStream_t stream) {
  const float* x     = (const float*)d_in[0];
  const float* Wih0  = (const float*)d_in[1];
  const float* Whh0  = (const float*)d_in[2];
  const float* bih0  = (const float*)d_in[3];
  const float* bhh0  = (const float*)d_in[4];
  const float* mask0 = (const float*)d_in[5];
  const float* Wih1  = (const float*)d_in[6];
  const float* Whh1  = (const float*)d_in[7];
  const float* bih1  = (const float*)d_in[8];
  const float* bhh1  = (const float*)d_in[9];
  const float* mask1 = (const float*)d_in[10];

  float* out = (float*)d_out;
  float* hn  = out + (long)B_ * T_ * H_;   // [2][64][256]
  float* cn  = hn + 2 * B_ * H_;

  char* w = (char*)d_ws;
  uint4*    wall0  = (uint4*)w;      w += 512 << 10;   // [32][1024] uint4
  uint4*    wall1  = (uint4*)w;      w += 512 << 10;
  _Float16* wf0    = (_Float16*)w;   w += 256 << 10;
  _Float16* wf1    = (_Float16*)w;   w += 512 << 10;
  float*    bias0  = (float*)w;      w += 4 << 10;
  float*    bias1  = (float*)w;      w += 4 << 10;
  float*    h0s    = (float*)w;      w += 64 << 10;
  float*    c0s    = (float*)w;      w += 64 << 10;
  float*    h1s    = (float*)w;      w += 64 << 10;
  float*    c1s    = (float*)w;      w += 64 << 10;
  _Float16* xw0    = (_Float16*)w;   w += (long)B_ * TC * G4 * 2;   // 16 MB
  _Float16* xw1    = (_Float16*)w;   w += (long)B_ * TC * G4 * 2;   // 16 MB
  _Float16* ybuf   = (_Float16*)w;   w += (long)B_ * TC * H_ * 2;   // 4 MB

  hipMemsetAsync(h0s, 0, 4 * (64 << 10), stream);

  prep_w<<<128, 256, 0, stream>>>(Whh0, wall0);
  prep_w<<<128, 256, 0, stream>>>(Whh1, wall1);
  prep_f16<<<512, 256, 0, stream>>>(Wih0, wf0, G4 * I_);
  prep_f16<<<1024, 256, 0, stream>>>(Wih1, wf1, G4 * H_);
  prep_bias<<<4, 256, 0, stream>>>(bih0, bhh0, bias0);
  prep_bias<<<4, 256, 0, stream>>>(bih1, bhh1, bias1);

  const int nchunk = T_ / TC;  // 16
  for (int k = 0; k <= nchunk; k++) {
    if (k < nchunk) {
      proj_kernel<I_, true><<<dim3(B_ * TC / 64, G4 / 64), 256, 0, stream>>>(
          x, wf0, bias0, xw0, k * TC);
    }
    ScanJob j0, j1;
    // layer 0, chunk k
    j0.xw = xw0; j0.wall = wall0; j0.mask = mask0;
    j0.hstate = h0s; j0.cstate = c0s;
    j0.ychunk = ybuf; j0.out = nullptr;
    j0.hn = (k == nchunk - 1) ? hn : nullptr;
    j0.cn = (k == nchunk - 1) ? cn : nullptr;
    j0.t0 = k * TC; j0.valid = (k < nchunk);
    // layer 1, chunk k-1
    j1.xw = xw1; j1.wall = wall1; j1.mask = mask1;
    j1.hstate = h1s; j1.cstate = c1s;
    j1.ychunk = nullptr; j1.out = out;
    j1.hn = (k == nchunk) ? hn + B_ * H_ : nullptr;
    j1.cn = (k == nchunk) ? cn + B_ * H_ : nullptr;
    j1.t0 = (k - 1) * TC; j1.valid = (k >= 1);

    scan_kernel<<<2 * B_, 512, 0, stream>>>(j0, j1);

    if (k < nchunk) {
      proj_kernel<H_, false><<<dim3(B_ * TC / 64, G4 / 64), 256, 0, stream>>>(
          ybuf, wf1, bias1, xw1, k * TC);
    }
  }
}